// Round 1
// baseline (402.072 us; speedup 1.0000x reference)
//
#include <hip/hip_runtime.h>

#define N_NODES 100000
#define N_EDGES 400000
#define HALF_E  200000
#define BN_EPS  1e-5f

// A_bf layout per node row: [in 200 | out 200 | x 200 | pad 40] = 640 bf16 (1280 B, 10 lines)
#define KTOT   640
#define CHUNKS 20
#define NPAD   208
#define GEMM_NBLK 782

typedef __bf16 bf16x8 __attribute__((ext_vector_type(8)));
typedef float  f32x4  __attribute__((ext_vector_type(4)));

// ---- workspace layout (bytes) ----
#define A_OFF      0ull                  // 100000*640*2 = 128,000,000
#define WT_OFF     128000000ull          // 208*640*2 = 266,240 (fragment-linear)
#define HIST_OFF   128266240ull          // 100000*4
#define CURSOR_OFF 128666240ull          // 100000*4
#define ZERO_BASE  HIST_OFF
#define ZERO_BYTES 800000ull             // hist+cursor
#define SCALE_OFF  129066240ull          // 200*4
#define SHIFT_OFF  129067040ull          // 200*4
#define ROWPTR_OFF 129069440ull          // 100001*4
#define BSUM_OFF   129469856ull          // 98*4
#define BOFF_OFF   129470248ull          // 98*4
#define REC_OFF    129470640ull          // 400000*16 = 6,400,000 (16B aligned)
#define PS_OFF     135870640ull          // 782*200*4 = 625,600
#define PQ_OFF     136496240ull          // 782*200*4 -> end 137,121,840

#define SCAN_NBLK 98                     // 98*1024 >= 100000

static __device__ __forceinline__ unsigned short f2bf(float f) {
    union { float f; unsigned u; } v; v.f = f;
    unsigned u = v.u;
    unsigned r = (u + 0x7fffu + ((u >> 16) & 1u)) >> 16;  // RNE
    return (unsigned short)r;
}
static __device__ __forceinline__ float bf2f(unsigned short s) {
    union { unsigned u; float f; } v; v.u = ((unsigned)s) << 16; return v.f;
}

// ---- pack Wt in FRAGMENT-LINEAR order: [chunk 20][nt 13][lane 64][e 8] ----
// lane -> n = nt*16 + (lane&15), k = chunk*32 + (lane>>4)*8 + e
// k-layout: [in 200 | out 200 | loop*loop_rel 200 | pad 40], bf16
__global__ __launch_bounds__(256) void pack_wt(
    const float* __restrict__ in_w, const float* __restrict__ out_w,
    const float* __restrict__ loop_w, const float* __restrict__ loop_rel,
    unsigned short* __restrict__ Wt) {
    int idx = blockIdx.x * 256 + threadIdx.x;      // 520*256 == 208*640
    int e = idx & 7;
    int idx8 = idx >> 3;
    int lane = idx8 & 63;
    int nt = (idx8 >> 6) % 13;
    int c = idx8 / (64 * 13);
    int n = nt * 16 + (lane & 15);
    int k = c * 32 + (lane >> 4) * 8 + e;
    float v = 0.f;
    if (n < 200) {
        if (k < 200)       v = in_w[k * 200 + n];
        else if (k < 400)  v = out_w[(k - 200) * 200 + n];
        else if (k < 600)  v = loop_w[(k - 400) * 200 + n] * loop_rel[k - 400];
    }
    Wt[idx] = f2bf(v);
}

// ---- write x-segment of A (bf16) + zero pad; also the gather source for aggregate ----
__global__ __launch_bounds__(256) void write_xseg(
    const float* __restrict__ x, unsigned short* __restrict__ A) {
    int v = blockIdx.x * 4 + (threadIdx.x >> 6);
    int lane = threadIdx.x & 63;
    unsigned short* ar = A + (size_t)v * KTOT;
    if (lane < 50) {
        float4 xv = *reinterpret_cast<const float4*>(x + v * 200 + lane * 4);
        ushort4 w = make_ushort4(f2bf(xv.x), f2bf(xv.y), f2bf(xv.z), f2bf(xv.w));
        *reinterpret_cast<ushort4*>(ar + 400 + lane * 4) = w;
    }
    if (lane < 40) ar[600 + lane] = 0;
}

// ---- CSR build: histogram by dst ----
__global__ __launch_bounds__(256) void hist_k(const int* __restrict__ edst,
                                              unsigned* __restrict__ hist) {
    int e = blockIdx.x * 256 + threadIdx.x;
    if (e < N_EDGES) atomicAdd(&hist[edst[e]], 1u);
}

// ---- scan pass 1: per-block sums ----
__global__ __launch_bounds__(1024) void scan_part(const unsigned* __restrict__ hist,
                                                  unsigned* __restrict__ bsum) {
    __shared__ unsigned s[1024];
    int idx = blockIdx.x * 1024 + threadIdx.x;
    s[threadIdx.x] = (idx < N_NODES) ? hist[idx] : 0u;
    __syncthreads();
    for (int off = 512; off > 0; off >>= 1) {
        if (threadIdx.x < off) s[threadIdx.x] += s[threadIdx.x + off];
        __syncthreads();
    }
    if (threadIdx.x == 0) bsum[blockIdx.x] = s[0];
}

// ---- scan pass 2: serial exclusive scan of 98 block sums ----
__global__ void scan_top(const unsigned* __restrict__ bsum, unsigned* __restrict__ boff,
                         unsigned* __restrict__ rowptr) {
    if (threadIdx.x == 0) {
        unsigned run = 0;
        for (int b = 0; b < SCAN_NBLK; ++b) { boff[b] = run; run += bsum[b]; }
        rowptr[N_NODES] = N_EDGES;
    }
}

// ---- scan pass 3: intra-block exclusive scan + offset ----
__global__ __launch_bounds__(1024) void scan_low(const unsigned* __restrict__ hist,
                                                 const unsigned* __restrict__ boff,
                                                 unsigned* __restrict__ rowptr) {
    __shared__ unsigned s[1024];
    int idx = blockIdx.x * 1024 + threadIdx.x;
    unsigned own = (idx < N_NODES) ? hist[idx] : 0u;
    s[threadIdx.x] = own;
    __syncthreads();
    for (int off = 1; off < 1024; off <<= 1) {
        unsigned t = 0;
        if ((int)threadIdx.x >= off) t = s[threadIdx.x - off];
        __syncthreads();
        if ((int)threadIdx.x >= off) s[threadIdx.x] += t;
        __syncthreads();
    }
    if (idx < N_NODES) rowptr[idx] = boff[blockIdx.x] + s[threadIdx.x] - own;
}

// ---- CSR fill: packed edge records {src, type, norm, dir} at sorted positions ----
__global__ __launch_bounds__(256) void fill_k(
    const int* __restrict__ edst, const int* __restrict__ esrc,
    const int* __restrict__ etyp, const float* __restrict__ norm,
    const unsigned* __restrict__ rowptr, unsigned* __restrict__ cursor,
    int4* __restrict__ recs) {
    int e = blockIdx.x * 256 + threadIdx.x;
    if (e < N_EDGES) {
        int d = edst[e];
        unsigned pos = rowptr[d] + atomicAdd(&cursor[d], 1u);
        recs[pos] = make_int4(esrc[e], etyp[e], __float_as_int(norm[e]), (e < HALF_E) ? 1 : 0);
    }
}

// ---- gather aggregation: one wave per dst node; bf16 x-rows from A's x-segment;
// ---- packed recs; 2 edges in flight per iteration ----
__global__ __launch_bounds__(256) void aggregate(
    const float* __restrict__ rel, const unsigned* __restrict__ rowptr,
    const int4* __restrict__ recs, unsigned short* __restrict__ A) {
    int v = blockIdx.x * 4 + (threadIdx.x >> 6);
    int lane = threadIdx.x & 63;
    bool act = lane < 50;                    // lane owns dims [lane*4, lane*4+4)
    int col = lane * 4;
    const unsigned short* Axs = A + 400;     // x-segment base
    float4 aI = make_float4(0.f, 0.f, 0.f, 0.f);
    float4 aO = make_float4(0.f, 0.f, 0.f, 0.f);
    int beg = rowptr[v], end = rowptr[v + 1];
    int j = beg;
    for (; j + 1 < end; j += 2) {
        int4 r0 = recs[j];
        int4 r1 = recs[j + 1];
        float n0 = __int_as_float(r0.z), n1 = __int_as_float(r1.z);
        if (act) {
            ushort4 x0 = *reinterpret_cast<const ushort4*>(Axs + (size_t)r0.x * KTOT + col);
            ushort4 x1 = *reinterpret_cast<const ushort4*>(Axs + (size_t)r1.x * KTOT + col);
            float4 rl0 = *reinterpret_cast<const float4*>(rel + r0.y * 200 + col);
            float4 rl1 = *reinterpret_cast<const float4*>(rel + r1.y * 200 + col);
            float4 m0 = make_float4(bf2f(x0.x) * rl0.x * n0, bf2f(x0.y) * rl0.y * n0,
                                    bf2f(x0.z) * rl0.z * n0, bf2f(x0.w) * rl0.w * n0);
            float4 m1 = make_float4(bf2f(x1.x) * rl1.x * n1, bf2f(x1.y) * rl1.y * n1,
                                    bf2f(x1.z) * rl1.z * n1, bf2f(x1.w) * rl1.w * n1);
            if (r0.w) { aI.x += m0.x; aI.y += m0.y; aI.z += m0.z; aI.w += m0.w; }
            else      { aO.x += m0.x; aO.y += m0.y; aO.z += m0.z; aO.w += m0.w; }
            if (r1.w) { aI.x += m1.x; aI.y += m1.y; aI.z += m1.z; aI.w += m1.w; }
            else      { aO.x += m1.x; aO.y += m1.y; aO.z += m1.z; aO.w += m1.w; }
        }
    }
    if (j < end) {
        int4 r0 = recs[j];
        float n0 = __int_as_float(r0.z);
        if (act) {
            ushort4 x0 = *reinterpret_cast<const ushort4*>(Axs + (size_t)r0.x * KTOT + col);
            float4 rl0 = *reinterpret_cast<const float4*>(rel + r0.y * 200 + col);
            float4 m0 = make_float4(bf2f(x0.x) * rl0.x * n0, bf2f(x0.y) * rl0.y * n0,
                                    bf2f(x0.z) * rl0.z * n0, bf2f(x0.w) * rl0.w * n0);
            if (r0.w) { aI.x += m0.x; aI.y += m0.y; aI.z += m0.z; aI.w += m0.w; }
            else      { aO.x += m0.x; aO.y += m0.y; aO.z += m0.z; aO.w += m0.w; }
        }
    }
    if (act) {
        unsigned short* ar = A + (size_t)v * KTOT;
        ushort4 wI = make_ushort4(f2bf(aI.x), f2bf(aI.y), f2bf(aI.z), f2bf(aI.w));
        ushort4 wO = make_ushort4(f2bf(aO.x), f2bf(aO.y), f2bf(aO.z), f2bf(aO.w));
        *reinterpret_cast<ushort4*>(ar + col)       = wI;
        *reinterpret_cast<ushort4*>(ar + 200 + col) = wO;
    }
}

// ---- GEMM: out[v][n] = A_bf[v][:] . Wt[n][:] / 3 ; per-block BN partials ----
// LDS-free main loop: A fragments loaded directly from global (no cross-block
// reuse -> staging buys nothing), W fragments loaded from the fragment-linear
// Wt (13.3 KB/chunk, identical for every wave on the chip -> L1/L2-resident).
// No __syncthreads() until the epilogue reduction -> no barrier drains, waves
// free-run and hide latency via TLP + compiler load pipelining.
__global__ __launch_bounds__(256) void gemm_nodes(
    const unsigned short* __restrict__ A, const unsigned short* __restrict__ Wt,
    float* __restrict__ out, float* __restrict__ PS, float* __restrict__ PQ) {
    __shared__ float redS[800];   // [4][200]
    __shared__ float redQ[800];
    int tid = threadIdx.x;
    int wave = tid >> 6, lane = tid & 63;
    int quad = lane >> 4, l15 = lane & 15;
    int row0 = blockIdx.x * 128;

    // rows this wave computes (same mapping as before): two 16-row groups
    int r0 = row0 + (wave * 2 + 0) * 16 + l15;
    int r1 = row0 + (wave * 2 + 1) * 16 + l15;
    // clamp load addresses for the (last-block-only) OOB rows; their acc values
    // are excluded from stores and BN stats by the m < N_NODES guard below.
    int cr0 = r0 < N_NODES ? r0 : (N_NODES - 1);
    int cr1 = r1 < N_NODES ? r1 : (N_NODES - 1);
    const unsigned short* pa0 = A + (size_t)cr0 * KTOT + quad * 8;
    const unsigned short* pa1 = A + (size_t)cr1 * KTOT + quad * 8;
    const bf16x8* wp = reinterpret_cast<const bf16x8*>(Wt) + lane;

    f32x4 acc[2][13];
#pragma unroll
    for (int i = 0; i < 2; ++i)
#pragma unroll
        for (int j = 0; j < 13; ++j) {
            acc[i][j].x = 0.f; acc[i][j].y = 0.f; acc[i][j].z = 0.f; acc[i][j].w = 0.f;
        }

    for (int c = 0; c < CHUNKS; ++c) {
        bf16x8 a0 = *reinterpret_cast<const bf16x8*>(pa0 + c * 32);
        bf16x8 a1 = *reinterpret_cast<const bf16x8*>(pa1 + c * 32);
        const bf16x8* wc = wp + c * (13 * 64);
#pragma unroll
        for (int nt = 0; nt < 13; ++nt) {
            bf16x8 b = wc[nt * 64];
            acc[0][nt] = __builtin_amdgcn_mfma_f32_16x16x32_bf16(a0, b, acc[0][nt], 0, 0, 0);
            acc[1][nt] = __builtin_amdgcn_mfma_f32_16x16x32_bf16(a1, b, acc[1][nt], 0, 0, 0);
        }
    }

    // epilogue: store /3; per-wave column stats -> LDS -> per-block partials
#pragma unroll
    for (int nt = 0; nt < 13; ++nt) {
        int n = nt * 16 + l15;
        float s = 0.f, q = 0.f;
#pragma unroll
        for (int i = 0; i < 2; ++i) {
            int mbase = row0 + (wave * 2 + i) * 16 + quad * 4;
#pragma unroll
            for (int r = 0; r < 4; ++r) {
                float val = acc[i][nt][r] * (1.f / 3.f);
                int m = mbase + r;
                if (m < N_NODES) {
                    if (n < 200) out[m * 200 + n] = val;
                    s += val; q += val * val;
                }
            }
        }
        s += __shfl_xor(s, 16); s += __shfl_xor(s, 32);
        q += __shfl_xor(q, 16); q += __shfl_xor(q, 32);
        if (lane < 16 && n < 200) {
            redS[wave * 200 + n] = s;
            redQ[wave * 200 + n] = q;
        }
    }
    __syncthreads();
    if (tid < 200) {
        float s = redS[tid] + redS[200 + tid] + redS[400 + tid] + redS[600 + tid];
        float q = redQ[tid] + redQ[200 + tid] + redQ[400 + tid] + redQ[600 + tid];
        PS[blockIdx.x * 200 + tid] = s;
        PQ[blockIdx.x * 200 + tid] = q;
    }
}

// ---- BN: reduce 782 partials per column, emit scale/shift. grid = 200 blocks ----
__global__ __launch_bounds__(256) void bn_reduce(
    const float* __restrict__ PS, const float* __restrict__ PQ,
    const float* __restrict__ gamma, const float* __restrict__ beta,
    float* __restrict__ scale, float* __restrict__ shift) {
    __shared__ float ls[256], lq[256];
    int c = blockIdx.x;
    float s = 0.f, q = 0.f;
    for (int b = threadIdx.x; b < GEMM_NBLK; b += 256) {
        s += PS[b * 200 + c];
        q += PQ[b * 200 + c];
    }
    ls[threadIdx.x] = s; lq[threadIdx.x] = q;
    __syncthreads();
    for (int off = 128; off > 0; off >>= 1) {
        if (threadIdx.x < off) {
            ls[threadIdx.x] += ls[threadIdx.x + off];
            lq[threadIdx.x] += lq[threadIdx.x + off];
        }
        __syncthreads();
    }
    if (threadIdx.x == 0) {
        float mean = ls[0] * (1.f / N_NODES);
        float var = lq[0] * (1.f / N_NODES) - mean * mean;
        float inv = rsqrtf(var + BN_EPS);
        float sc = inv * gamma[c];
        scale[c] = sc;
        shift[c] = beta[c] - mean * sc;
    }
}

__global__ __launch_bounds__(256) void bn_apply(
    float* __restrict__ h, const float* __restrict__ scale, const float* __restrict__ shift) {
    __shared__ float ssc[200], ssh[200];
    if (threadIdx.x < 200) { ssc[threadIdx.x] = scale[threadIdx.x]; ssh[threadIdx.x] = shift[threadIdx.x]; }
    __syncthreads();
    const int total4 = N_NODES * 200 / 4;  // 5,000,000 float4
    int stride = gridDim.x * blockDim.x;
    for (int i = blockIdx.x * blockDim.x + threadIdx.x; i < total4; i += stride) {
        int c = (i % 50) * 4;
        float4 v = reinterpret_cast<float4*>(h)[i];
        v.x = v.x * ssc[c + 0] + ssh[c + 0];
        v.y = v.y * ssc[c + 1] + ssh[c + 1];
        v.z = v.z * ssc[c + 2] + ssh[c + 2];
        v.w = v.w * ssc[c + 3] + ssh[c + 3];
        reinterpret_cast<float4*>(h)[i] = v;
    }
}

// ---- rel_out = rel_repr @ w_rel (200x200 @ 200x200), fp32 exact ----
__global__ __launch_bounds__(256) void rel_out_k(
    const float* __restrict__ rel, const float* __restrict__ w, float* __restrict__ out) {
    int i = blockIdx.x, j = threadIdx.x;
    if (j < 200) {
        float acc = 0.f;
        for (int k = 0; k < 200; ++k) acc += rel[i * 200 + k] * w[k * 200 + j];
        out[i * 200 + j] = acc;
    }
}

extern "C" void kernel_launch(void* const* d_in, const int* in_sizes, int n_in,
                              void* d_out, int out_size, void* d_ws, size_t ws_size,
                              hipStream_t stream) {
    const float* x         = (const float*)d_in[0];
    const float* rel_repr  = (const float*)d_in[1];
    const float* edge_norm = (const float*)d_in[2];
    const float* in_w      = (const float*)d_in[3];
    const float* out_w     = (const float*)d_in[4];
    const float* loop_w    = (const float*)d_in[5];
    const float* loop_rel  = (const float*)d_in[6];
    const float* w_rel     = (const float*)d_in[7];
    const float* bn_gamma  = (const float*)d_in[8];
    const float* bn_beta   = (const float*)d_in[9];
    const int* edge_src    = (const int*)d_in[10];
    const int* edge_dst    = (const int*)d_in[11];
    const int* edge_type   = (const int*)d_in[12];

    float* out = (float*)d_out;
    char* ws = (char*)d_ws;
    unsigned short* A  = (unsigned short*)(ws + A_OFF);
    unsigned short* Wt = (unsigned short*)(ws + WT_OFF);
    unsigned* hist     = (unsigned*)(ws + HIST_OFF);
    unsigned* cursor   = (unsigned*)(ws + CURSOR_OFF);
    float* scale       = (float*)(ws + SCALE_OFF);
    float* shift       = (float*)(ws + SHIFT_OFF);
    unsigned* rowptr   = (unsigned*)(ws + ROWPTR_OFF);
    unsigned* bsum     = (unsigned*)(ws + BSUM_OFF);
    unsigned* boff     = (unsigned*)(ws + BOFF_OFF);
    int4* recs         = (int4*)(ws + REC_OFF);
    float* PS          = (float*)(ws + PS_OFF);
    float* PQ          = (float*)(ws + PQ_OFF);

    hipMemsetAsync(ws + ZERO_BASE, 0, ZERO_BYTES, stream);  // hist+cursor
    pack_wt<<<520, 256, 0, stream>>>(in_w, out_w, loop_w, loop_rel, Wt);
    write_xseg<<<25000, 256, 0, stream>>>(x, A);
    hist_k<<<1563, 256, 0, stream>>>(edge_dst, hist);
    scan_part<<<SCAN_NBLK, 1024, 0, stream>>>(hist, bsum);
    scan_top<<<1, 64, 0, stream>>>(bsum, boff, rowptr);
    scan_low<<<SCAN_NBLK, 1024, 0, stream>>>(hist, boff, rowptr);
    fill_k<<<1563, 256, 0, stream>>>(edge_dst, edge_src, edge_type, edge_norm,
                                     rowptr, cursor, recs);
    aggregate<<<25000, 256, 0, stream>>>(rel_repr, rowptr, recs, A);
    gemm_nodes<<<GEMM_NBLK, 256, 0, stream>>>(A, Wt, out, PS, PQ);
    bn_reduce<<<200, 256, 0, stream>>>(PS, PQ, bn_gamma, bn_beta, scale, shift);
    bn_apply<<<1024, 256, 0, stream>>>(out, scale, shift);
    rel_out_k<<<200, 256, 0, stream>>>(rel_repr, w_rel, out + 20000000);
}

// Round 2
// 357.944 us; speedup vs baseline: 1.1233x; 1.1233x over previous
//
#include <hip/hip_runtime.h>

#define N_NODES 100000
#define N_EDGES 400000
#define HALF_E  200000
#define BN_EPS  1e-5f

// A_bf layout per node row: [in 200 | out 200 | x 200 | pad 40] = 640 bf16 (1280 B)
// Within each 32-bf16 (64 B) chunk, 16B slot s of row v is stored at physical
// slot s ^ ((v>>1)&3)  -> linear global_load_lds staging + XOR'd ds_read_b128
// gives conflict-free (2-way) LDS reads in the GEMM (rule 21: source-side
// pre-swizzle + same XOR on read).
#define KTOT   640
#define CHUNKS 20
#define GEMM_NBLK 782

// LDS tile: per buffer  A [0, 8192) = 128 rows x 64 B,  W [8192, 21504) = 208 rows x 64 B
#define LDS_BUF_BYTES 21504
#define LDS_W_OFF     8192

typedef __bf16 bf16x8 __attribute__((ext_vector_type(8)));
typedef float  f32x4  __attribute__((ext_vector_type(4)));

// ---- workspace layout (bytes) ----
#define A_OFF      0ull                  // 100000*640*2 = 128,000,000
#define WT_OFF     128000000ull          // 20*208*64 B = 266,240 (chunk-major, pre-swizzled)
#define HIST_OFF   128266240ull          // 100000*4
#define CURSOR_OFF 128666240ull          // 100000*4
#define ZERO_BASE  HIST_OFF
#define ZERO_BYTES 800000ull             // hist+cursor
#define SCALE_OFF  129066240ull          // 200*4
#define SHIFT_OFF  129067040ull          // 200*4
#define ROWPTR_OFF 129069440ull          // 100001*4
#define BSUM_OFF   129469856ull          // 98*4
#define BOFF_OFF   129470248ull          // 98*4
#define REC_OFF    129470640ull          // 400000*16 = 6,400,000 (16B aligned)
#define PS_OFF     135870640ull          // 782*200*4 = 625,600
#define PQ_OFF     136496240ull          // 782*200*4 -> end 137,121,840

#define SCAN_NBLK 98                     // 98*1024 >= 100000

static __device__ __forceinline__ unsigned short f2bf(float f) {
    union { float f; unsigned u; } v; v.f = f;
    unsigned u = v.u;
    unsigned r = (u + 0x7fffu + ((u >> 16) & 1u)) >> 16;  // RNE
    return (unsigned short)r;
}
static __device__ __forceinline__ float bf2f(unsigned short s) {
    union { unsigned u; float f; } v; v.u = ((unsigned)s) << 16; return v.f;
}

// physical bf16 offset of logical k within a row, given row swizzle s = (v>>1)&3
static __device__ __forceinline__ int swzk(int k, int s) {
    return (k & ~31) | (k & 7) | ((((k >> 3) & 3) ^ s) << 3);
}

// async global->LDS, 16 B per lane, linear LDS dest (wave-uniform base + lane*16)
static __device__ __forceinline__ void gload16(const void* g, void* l) {
    __builtin_amdgcn_global_load_lds(
        (const __attribute__((address_space(1))) void*)g,
        (__attribute__((address_space(3))) void*)l, 16, 0, 0);
}

// ---- pack Wt chunk-major, pre-swizzled: [c 20][n 208][slot_phys 4][8 bf16] ----
// value at (n, k): k-layout [in 200 | out 200 | loop*loop_rel 200 | pad 40]
__global__ __launch_bounds__(256) void pack_wt(
    const float* __restrict__ in_w, const float* __restrict__ out_w,
    const float* __restrict__ loop_w, const float* __restrict__ loop_rel,
    unsigned short* __restrict__ Wt) {
    int idx = blockIdx.x * 256 + threadIdx.x;      // 520*256 == 20*208*32
    int e = idx & 7;
    int t = idx >> 3;
    int sp = t & 3;
    int t2 = t >> 2;
    int n = t2 % 208;
    int c = t2 / 208;
    int sl = sp ^ ((n >> 1) & 3);
    int k = c * 32 + sl * 8 + e;
    float v = 0.f;
    if (n < 200) {
        if (k < 200)       v = in_w[k * 200 + n];
        else if (k < 400)  v = out_w[(k - 200) * 200 + n];
        else if (k < 600)  v = loop_w[(k - 400) * 200 + n] * loop_rel[k - 400];
    }
    Wt[idx] = f2bf(v);
}

// ---- write x-segment of A (bf16, swizzled) + zero pad ----
__global__ __launch_bounds__(256) void write_xseg(
    const float* __restrict__ x, unsigned short* __restrict__ A) {
    int v = blockIdx.x * 4 + (threadIdx.x >> 6);
    int lane = threadIdx.x & 63;
    int s = (v >> 1) & 3;
    unsigned short* ar = A + (size_t)v * KTOT;
    if (lane < 50) {
        float4 xv = *reinterpret_cast<const float4*>(x + v * 200 + lane * 4);
        ushort4 w = make_ushort4(f2bf(xv.x), f2bf(xv.y), f2bf(xv.z), f2bf(xv.w));
        *reinterpret_cast<ushort4*>(ar + swzk(400 + lane * 4, s)) = w;
    }
    if (lane < 10)
        *reinterpret_cast<ushort4*>(ar + swzk(600 + lane * 4, s)) = make_ushort4(0, 0, 0, 0);
}

// ---- CSR build: histogram by dst ----
__global__ __launch_bounds__(256) void hist_k(const int* __restrict__ edst,
                                              unsigned* __restrict__ hist) {
    int e = blockIdx.x * 256 + threadIdx.x;
    if (e < N_EDGES) atomicAdd(&hist[edst[e]], 1u);
}

// ---- scan pass 1: per-block sums ----
__global__ __launch_bounds__(1024) void scan_part(const unsigned* __restrict__ hist,
                                                  unsigned* __restrict__ bsum) {
    __shared__ unsigned s[1024];
    int idx = blockIdx.x * 1024 + threadIdx.x;
    s[threadIdx.x] = (idx < N_NODES) ? hist[idx] : 0u;
    __syncthreads();
    for (int off = 512; off > 0; off >>= 1) {
        if (threadIdx.x < off) s[threadIdx.x] += s[threadIdx.x + off];
        __syncthreads();
    }
    if (threadIdx.x == 0) bsum[blockIdx.x] = s[0];
}

// ---- scan pass 2: serial exclusive scan of 98 block sums ----
__global__ void scan_top(const unsigned* __restrict__ bsum, unsigned* __restrict__ boff,
                         unsigned* __restrict__ rowptr) {
    if (threadIdx.x == 0) {
        unsigned run = 0;
        for (int b = 0; b < SCAN_NBLK; ++b) { boff[b] = run; run += bsum[b]; }
        rowptr[N_NODES] = N_EDGES;
    }
}

// ---- scan pass 3: intra-block exclusive scan + offset ----
__global__ __launch_bounds__(1024) void scan_low(const unsigned* __restrict__ hist,
                                                 const unsigned* __restrict__ boff,
                                                 unsigned* __restrict__ rowptr) {
    __shared__ unsigned s[1024];
    int idx = blockIdx.x * 1024 + threadIdx.x;
    unsigned own = (idx < N_NODES) ? hist[idx] : 0u;
    s[threadIdx.x] = own;
    __syncthreads();
    for (int off = 1; off < 1024; off <<= 1) {
        unsigned t = 0;
        if ((int)threadIdx.x >= off) t = s[threadIdx.x - off];
        __syncthreads();
        if ((int)threadIdx.x >= off) s[threadIdx.x] += t;
        __syncthreads();
    }
    if (idx < N_NODES) rowptr[idx] = boff[blockIdx.x] + s[threadIdx.x] - own;
}

// ---- CSR fill: packed edge records {src, type, norm, dir} at sorted positions ----
__global__ __launch_bounds__(256) void fill_k(
    const int* __restrict__ edst, const int* __restrict__ esrc,
    const int* __restrict__ etyp, const float* __restrict__ norm,
    const unsigned* __restrict__ rowptr, unsigned* __restrict__ cursor,
    int4* __restrict__ recs) {
    int e = blockIdx.x * 256 + threadIdx.x;
    if (e < N_EDGES) {
        int d = edst[e];
        unsigned pos = rowptr[d] + atomicAdd(&cursor[d], 1u);
        recs[pos] = make_int4(esrc[e], etyp[e], __float_as_int(norm[e]), (e < HALF_E) ? 1 : 0);
    }
}

// ---- gather aggregation: one wave per dst node; swizzled bf16 x-rows ----
__global__ __launch_bounds__(256) void aggregate(
    const float* __restrict__ rel, const unsigned* __restrict__ rowptr,
    const int4* __restrict__ recs, unsigned short* __restrict__ A) {
    int v = blockIdx.x * 4 + (threadIdx.x >> 6);
    int lane = threadIdx.x & 63;
    bool act = lane < 50;                    // lane owns dims [lane*4, lane*4+4)
    int col = lane * 4;
    int kx = 400 + col;                      // logical x position
    int kxb = (kx & ~31) | (kx & 7);         // swizzle-invariant part
    int kxs = (kx >> 3) & 3;                 // logical slot
    float4 aI = make_float4(0.f, 0.f, 0.f, 0.f);
    float4 aO = make_float4(0.f, 0.f, 0.f, 0.f);
    int beg = rowptr[v], end = rowptr[v + 1];
    int j = beg;
    for (; j + 1 < end; j += 2) {
        int4 r0 = recs[j];
        int4 r1 = recs[j + 1];
        float n0 = __int_as_float(r0.z), n1 = __int_as_float(r1.z);
        if (act) {
            int s0 = (r0.x >> 1) & 3, s1 = (r1.x >> 1) & 3;
            ushort4 x0 = *reinterpret_cast<const ushort4*>(
                A + (size_t)r0.x * KTOT + kxb + ((kxs ^ s0) << 3));
            ushort4 x1 = *reinterpret_cast<const ushort4*>(
                A + (size_t)r1.x * KTOT + kxb + ((kxs ^ s1) << 3));
            float4 rl0 = *reinterpret_cast<const float4*>(rel + r0.y * 200 + col);
            float4 rl1 = *reinterpret_cast<const float4*>(rel + r1.y * 200 + col);
            float4 m0 = make_float4(bf2f(x0.x) * rl0.x * n0, bf2f(x0.y) * rl0.y * n0,
                                    bf2f(x0.z) * rl0.z * n0, bf2f(x0.w) * rl0.w * n0);
            float4 m1 = make_float4(bf2f(x1.x) * rl1.x * n1, bf2f(x1.y) * rl1.y * n1,
                                    bf2f(x1.z) * rl1.z * n1, bf2f(x1.w) * rl1.w * n1);
            if (r0.w) { aI.x += m0.x; aI.y += m0.y; aI.z += m0.z; aI.w += m0.w; }
            else      { aO.x += m0.x; aO.y += m0.y; aO.z += m0.z; aO.w += m0.w; }
            if (r1.w) { aI.x += m1.x; aI.y += m1.y; aI.z += m1.z; aI.w += m1.w; }
            else      { aO.x += m1.x; aO.y += m1.y; aO.z += m1.z; aO.w += m1.w; }
        }
    }
    if (j < end) {
        int4 r0 = recs[j];
        float n0 = __int_as_float(r0.z);
        if (act) {
            int s0 = (r0.x >> 1) & 3;
            ushort4 x0 = *reinterpret_cast<const ushort4*>(
                A + (size_t)r0.x * KTOT + kxb + ((kxs ^ s0) << 3));
            float4 rl0 = *reinterpret_cast<const float4*>(rel + r0.y * 200 + col);
            float4 m0 = make_float4(bf2f(x0.x) * rl0.x * n0, bf2f(x0.y) * rl0.y * n0,
                                    bf2f(x0.z) * rl0.z * n0, bf2f(x0.w) * rl0.w * n0);
            if (r0.w) { aI.x += m0.x; aI.y += m0.y; aI.z += m0.z; aI.w += m0.w; }
            else      { aO.x += m0.x; aO.y += m0.y; aO.z += m0.z; aO.w += m0.w; }
        }
    }
    if (act) {
        int sv = (v >> 1) & 3;
        unsigned short* ar = A + (size_t)v * KTOT;
        ushort4 wI = make_ushort4(f2bf(aI.x), f2bf(aI.y), f2bf(aI.z), f2bf(aI.w));
        ushort4 wO = make_ushort4(f2bf(aO.x), f2bf(aO.y), f2bf(aO.z), f2bf(aO.w));
        *reinterpret_cast<ushort4*>(ar + swzk(col, sv))       = wI;
        *reinterpret_cast<ushort4*>(ar + swzk(200 + col, sv)) = wO;
    }
}

// ---- GEMM: out[v][n] = A_bf[v][:] . Wt[n][:] / 3 ; per-block BN partials ----
// 2-phase double-buffered pipeline (guide T3 minimum form):
//   STAGE(buf^1, c+1) via global_load_lds   <- loads fly during MFMA phase
//   ds_read buf (XOR-swizzled, 2-way=free) + 26 MFMA
//   one __syncthreads per chunk (vmcnt(0)+barrier)
__global__ __launch_bounds__(256) void gemm_nodes(
    const unsigned short* __restrict__ A, const unsigned short* __restrict__ Wt,
    float* __restrict__ out, float* __restrict__ PS, float* __restrict__ PQ) {
    __shared__ __align__(16) char lds[2][LDS_BUF_BYTES];
    int tid = threadIdx.x;
    int wave = tid >> 6, lane = tid & 63;
    int quad = lane >> 4, l15 = lane & 15;
    int row0 = blockIdx.x * 128;
    int pslot16 = ((quad ^ ((l15 >> 1) & 3)) << 4);   // physical 16B slot for reads

    // staging sources: wave stages A rows [(wave*2+p)*16, +16), lane -> (row lane>>2, slot lane&3)
    int sv0 = row0 + (wave * 2 + 0) * 16 + (lane >> 2);
    int sv1 = row0 + (wave * 2 + 1) * 16 + (lane >> 2);
    if (sv0 >= N_NODES) sv0 = N_NODES - 1;   // clamp; excluded from out/stats below
    if (sv1 >= N_NODES) sv1 = N_NODES - 1;
    const char* Ab = (const char*)A;
    const char* srcA0 = Ab + (size_t)sv0 * 1280 + (lane & 3) * 16;
    const char* srcA1 = Ab + (size_t)sv1 * 1280 + (lane & 3) * 16;
    const char* Wb = (const char*)Wt + lane * 16;

    // LDS read offsets
    int rdA0 = ((wave * 2 + 0) * 16 + l15) * 64 + pslot16;
    int rdA1 = ((wave * 2 + 1) * 16 + l15) * 64 + pslot16;
    int rdB  = LDS_W_OFF + l15 * 64 + pslot16;

    f32x4 acc[2][13];
#pragma unroll
    for (int i = 0; i < 2; ++i)
#pragma unroll
        for (int j = 0; j < 13; ++j) {
            acc[i][j].x = 0.f; acc[i][j].y = 0.f; acc[i][j].z = 0.f; acc[i][j].w = 0.f;
        }

    // prologue: stage chunk 0 into buf 0
    {
        char* lb = lds[0];
        gload16(srcA0, lb + (wave * 2 + 0) * 1024);
        gload16(srcA1, lb + (wave * 2 + 1) * 1024);
#pragma unroll
        for (int i = wave; i < 13; i += 4)
            gload16(Wb + i * 1024, lb + LDS_W_OFF + i * 1024);
    }
    __syncthreads();

    int cur = 0;
    for (int c = 0; c < CHUNKS; ++c) {
        if (c + 1 < CHUNKS) {            // stage next chunk into other buffer
            char* lb = lds[cur ^ 1];
            gload16(srcA0 + (c + 1) * 64, lb + (wave * 2 + 0) * 1024);
            gload16(srcA1 + (c + 1) * 64, lb + (wave * 2 + 1) * 1024);
            const char* wsrc = Wb + (size_t)(c + 1) * 13312;
#pragma unroll
            for (int i = wave; i < 13; i += 4)
                gload16(wsrc + i * 1024, lb + LDS_W_OFF + i * 1024);
        }
        const char* lb = lds[cur];
        bf16x8 a0 = *reinterpret_cast<const bf16x8*>(lb + rdA0);
        bf16x8 a1 = *reinterpret_cast<const bf16x8*>(lb + rdA1);
#pragma unroll
        for (int nt = 0; nt < 13; ++nt) {
            bf16x8 b = *reinterpret_cast<const bf16x8*>(lb + rdB + nt * 1024);
            acc[0][nt] = __builtin_amdgcn_mfma_f32_16x16x32_bf16(a0, b, acc[0][nt], 0, 0, 0);
            acc[1][nt] = __builtin_amdgcn_mfma_f32_16x16x32_bf16(a1, b, acc[1][nt], 0, 0, 0);
        }
        __syncthreads();
        cur ^= 1;
    }

    // epilogue: store /3; per-wave column stats -> LDS -> per-block partials
    float* redS = reinterpret_cast<float*>(lds[0]);        // [4][200]
    float* redQ = reinterpret_cast<float*>(lds[0]) + 800;  // [4][200]
#pragma unroll
    for (int nt = 0; nt < 13; ++nt) {
        int n = nt * 16 + l15;
        float s = 0.f, q = 0.f;
#pragma unroll
        for (int i = 0; i < 2; ++i) {
            int mbase = row0 + (wave * 2 + i) * 16 + quad * 4;
#pragma unroll
            for (int r = 0; r < 4; ++r) {
                float val = acc[i][nt][r] * (1.f / 3.f);
                int m = mbase + r;
                if (m < N_NODES) {
                    if (n < 200) out[m * 200 + n] = val;
                    s += val; q += val * val;
                }
            }
        }
        s += __shfl_xor(s, 16); s += __shfl_xor(s, 32);
        q += __shfl_xor(q, 16); q += __shfl_xor(q, 32);
        if (lane < 16 && n < 200) {
            redS[wave * 200 + n] = s;
            redQ[wave * 200 + n] = q;
        }
    }
    __syncthreads();
    if (tid < 200) {
        float s = redS[tid] + redS[200 + tid] + redS[400 + tid] + redS[600 + tid];
        float q = redQ[tid] + redQ[200 + tid] + redQ[400 + tid] + redQ[600 + tid];
        PS[blockIdx.x * 200 + tid] = s;
        PQ[blockIdx.x * 200 + tid] = q;
    }
}

// ---- BN: reduce 782 partials per column, emit scale/shift. grid = 200 blocks ----
__global__ __launch_bounds__(256) void bn_reduce(
    const float* __restrict__ PS, const float* __restrict__ PQ,
    const float* __restrict__ gamma, const float* __restrict__ beta,
    float* __restrict__ scale, float* __restrict__ shift) {
    __shared__ float ls[256], lq[256];
    int c = blockIdx.x;
    float s = 0.f, q = 0.f;
    for (int b = threadIdx.x; b < GEMM_NBLK; b += 256) {
        s += PS[b * 200 + c];
        q += PQ[b * 200 + c];
    }
    ls[threadIdx.x] = s; lq[threadIdx.x] = q;
    __syncthreads();
    for (int off = 128; off > 0; off >>= 1) {
        if (threadIdx.x < off) {
            ls[threadIdx.x] += ls[threadIdx.x + off];
            lq[threadIdx.x] += lq[threadIdx.x + off];
        }
        __syncthreads();
    }
    if (threadIdx.x == 0) {
        float mean = ls[0] * (1.f / N_NODES);
        float var = lq[0] * (1.f / N_NODES) - mean * mean;
        float inv = rsqrtf(var + BN_EPS);
        float sc = inv * gamma[c];
        scale[c] = sc;
        shift[c] = beta[c] - mean * sc;
    }
}

__global__ __launch_bounds__(256) void bn_apply(
    float* __restrict__ h, const float* __restrict__ scale, const float* __restrict__ shift) {
    __shared__ float ssc[200], ssh[200];
    if (threadIdx.x < 200) { ssc[threadIdx.x] = scale[threadIdx.x]; ssh[threadIdx.x] = shift[threadIdx.x]; }
    __syncthreads();
    const int total4 = N_NODES * 200 / 4;  // 5,000,000 float4
    int stride = gridDim.x * blockDim.x;
    for (int i = blockIdx.x * blockDim.x + threadIdx.x; i < total4; i += stride) {
        int c = (i % 50) * 4;
        float4 v = reinterpret_cast<float4*>(h)[i];
        v.x = v.x * ssc[c + 0] + ssh[c + 0];
        v.y = v.y * ssc[c + 1] + ssh[c + 1];
        v.z = v.z * ssc[c + 2] + ssh[c + 2];
        v.w = v.w * ssc[c + 3] + ssh[c + 3];
        reinterpret_cast<float4*>(h)[i] = v;
    }
}

// ---- rel_out = rel_repr @ w_rel (200x200 @ 200x200), fp32 exact ----
__global__ __launch_bounds__(256) void rel_out_k(
    const float* __restrict__ rel, const float* __restrict__ w, float* __restrict__ out) {
    int i = blockIdx.x, j = threadIdx.x;
    if (j < 200) {
        float acc = 0.f;
        for (int k = 0; k < 200; ++k) acc += rel[i * 200 + k] * w[k * 200 + j];
        out[i * 200 + j] = acc;
    }
}

extern "C" void kernel_launch(void* const* d_in, const int* in_sizes, int n_in,
                              void* d_out, int out_size, void* d_ws, size_t ws_size,
                              hipStream_t stream) {
    const float* x         = (const float*)d_in[0];
    const float* rel_repr  = (const float*)d_in[1];
    const float* edge_norm = (const float*)d_in[2];
    const float* in_w      = (const float*)d_in[3];
    const float* out_w     = (const float*)d_in[4];
    const float* loop_w    = (const float*)d_in[5];
    const float* loop_rel  = (const float*)d_in[6];
    const float* w_rel     = (const float*)d_in[7];
    const float* bn_gamma  = (const float*)d_in[8];
    const float* bn_beta   = (const float*)d_in[9];
    const int* edge_src    = (const int*)d_in[10];
    const int* edge_dst    = (const int*)d_in[11];
    const int* edge_type   = (const int*)d_in[12];

    float* out = (float*)d_out;
    char* ws = (char*)d_ws;
    unsigned short* A  = (unsigned short*)(ws + A_OFF);
    unsigned short* Wt = (unsigned short*)(ws + WT_OFF);
    unsigned* hist     = (unsigned*)(ws + HIST_OFF);
    unsigned* cursor   = (unsigned*)(ws + CURSOR_OFF);
    float* scale       = (float*)(ws + SCALE_OFF);
    float* shift       = (float*)(ws + SHIFT_OFF);
    unsigned* rowptr   = (unsigned*)(ws + ROWPTR_OFF);
    unsigned* bsum     = (unsigned*)(ws + BSUM_OFF);
    unsigned* boff     = (unsigned*)(ws + BOFF_OFF);
    int4* recs         = (int4*)(ws + REC_OFF);
    float* PS          = (float*)(ws + PS_OFF);
    float* PQ          = (float*)(ws + PQ_OFF);

    hipMemsetAsync(ws + ZERO_BASE, 0, ZERO_BYTES, stream);  // hist+cursor
    pack_wt<<<520, 256, 0, stream>>>(in_w, out_w, loop_w, loop_rel, Wt);
    write_xseg<<<25000, 256, 0, stream>>>(x, A);
    hist_k<<<1563, 256, 0, stream>>>(edge_dst, hist);
    scan_part<<<SCAN_NBLK, 1024, 0, stream>>>(hist, bsum);
    scan_top<<<1, 64, 0, stream>>>(bsum, boff, rowptr);
    scan_low<<<SCAN_NBLK, 1024, 0, stream>>>(hist, boff, rowptr);
    fill_k<<<1563, 256, 0, stream>>>(edge_dst, edge_src, edge_type, edge_norm,
                                     rowptr, cursor, recs);
    aggregate<<<25000, 256, 0, stream>>>(rel_repr, rowptr, recs, A);
    gemm_nodes<<<GEMM_NBLK, 256, 0, stream>>>(A, Wt, out, PS, PQ);
    bn_reduce<<<200, 256, 0, stream>>>(PS, PQ, bn_gamma, bn_beta, scale, shift);
    bn_apply<<<1024, 256, 0, stream>>>(out, scale, shift);
    rel_out_k<<<200, 256, 0, stream>>>(rel_repr, w_rel, out + 20000000);
}

// Round 3
// 357.518 us; speedup vs baseline: 1.1246x; 1.0012x over previous
//
#include <hip/hip_runtime.h>

#define N_NODES 100000
#define N_EDGES 400000
#define HALF_E  200000
#define BN_EPS  1e-5f

// A_bf layout per node row: [in 200 | out 200 | x 200 | pad 40] = 640 bf16 (1280 B)
// Within each 32-bf16 (64 B) chunk, 16B slot s of row v is stored at physical
// slot s ^ ((v>>1)&3)  -> linear global_load_lds staging + XOR'd ds_read_b128
// gives conflict-free (2-way) LDS reads in the GEMM (rule 21: source-side
// pre-swizzle + same XOR on read).
#define KTOT   640
#define CHUNKS 20
#define GEMM_NBLK 782

// LDS tile: per buffer  A [0, 8192) = 128 rows x 64 B,  W [8192, 21504) = 208 rows x 64 B
#define LDS_BUF_BYTES 21504
#define LDS_W_OFF     8192

#define XSEG_NBLK 25000
#define PACK_NBLK 520
#define PREP_NBLK (XSEG_NBLK + PACK_NBLK)

typedef __bf16 bf16x8 __attribute__((ext_vector_type(8)));
typedef float  f32x4  __attribute__((ext_vector_type(4)));

// ---- workspace layout (bytes) ----
#define A_OFF      0ull                  // 100000*640*2 = 128,000,000
#define WT_OFF     128000000ull          // 20*208*64 B = 266,240 (chunk-major, pre-swizzled)
#define HIST_OFF   128266240ull          // 100000*4
#define CURSOR_OFF 128666240ull          // 100000*4
#define ZERO_BASE  HIST_OFF
#define ZERO_BYTES 800000ull             // hist+cursor
#define SCALE_OFF  129066240ull          // 200*4
#define SHIFT_OFF  129067040ull          // 200*4
#define ROWPTR_OFF 129069440ull          // 100001*4
#define BSUM_OFF   129469856ull          // 98*4
#define BOFF_OFF   129470248ull          // 98*4
#define REC_OFF    129470640ull          // 400000*16 = 6,400,000 (16B aligned)
#define PS_OFF     135870640ull          // 782*200*4 = 625,600
#define PQ_OFF     136496240ull          // 782*200*4 -> end 137,121,840

#define SCAN_NBLK 98                     // 98*1024 >= 100000

static __device__ __forceinline__ unsigned short f2bf(float f) {
    union { float f; unsigned u; } v; v.f = f;
    unsigned u = v.u;
    unsigned r = (u + 0x7fffu + ((u >> 16) & 1u)) >> 16;  // RNE
    return (unsigned short)r;
}
static __device__ __forceinline__ float bf2f(unsigned short s) {
    union { unsigned u; float f; } v; v.u = ((unsigned)s) << 16; return v.f;
}

// physical bf16 offset of logical k within a row, given row swizzle s = (v>>1)&3
static __device__ __forceinline__ int swzk(int k, int s) {
    return (k & ~31) | (k & 7) | ((((k >> 3) & 3) ^ s) << 3);
}

// async global->LDS, 16 B per lane, linear LDS dest (wave-uniform base + lane*16)
static __device__ __forceinline__ void gload16(const void* g, void* l) {
    __builtin_amdgcn_global_load_lds(
        (const __attribute__((address_space(1))) void*)g,
        (__attribute__((address_space(3))) void*)l, 16, 0, 0);
}

// ---- fused prep: blocks [0,25000) write swizzled x-segment of A + zero pad;
// ---- blocks [25000,25520) pack Wt chunk-major pre-swizzled ----
__global__ __launch_bounds__(256) void prep_k(
    const float* __restrict__ x,
    const float* __restrict__ in_w, const float* __restrict__ out_w,
    const float* __restrict__ loop_w, const float* __restrict__ loop_rel,
    unsigned short* __restrict__ A, unsigned short* __restrict__ Wt) {
    int b = blockIdx.x;
    if (b < XSEG_NBLK) {
        int v = b * 4 + (threadIdx.x >> 6);
        int lane = threadIdx.x & 63;
        int s = (v >> 1) & 3;
        unsigned short* ar = A + (size_t)v * KTOT;
        if (lane < 50) {
            float4 xv = *reinterpret_cast<const float4*>(x + v * 200 + lane * 4);
            ushort4 w = make_ushort4(f2bf(xv.x), f2bf(xv.y), f2bf(xv.z), f2bf(xv.w));
            *reinterpret_cast<ushort4*>(ar + swzk(400 + lane * 4, s)) = w;
        }
        if (lane < 10)
            *reinterpret_cast<ushort4*>(ar + swzk(600 + lane * 4, s)) = make_ushort4(0, 0, 0, 0);
    } else {
        // Wt layout: [c 20][n 208][slot_phys 4][8 bf16]
        int idx = (b - XSEG_NBLK) * 256 + threadIdx.x;   // 520*256 == 20*208*32
        int e = idx & 7;
        int t = idx >> 3;
        int sp = t & 3;
        int t2 = t >> 2;
        int n = t2 % 208;
        int c = t2 / 208;
        int sl = sp ^ ((n >> 1) & 3);
        int k = c * 32 + sl * 8 + e;
        float v = 0.f;
        if (n < 200) {
            if (k < 200)       v = in_w[k * 200 + n];
            else if (k < 400)  v = out_w[(k - 200) * 200 + n];
            else if (k < 600)  v = loop_w[(k - 400) * 200 + n] * loop_rel[k - 400];
        }
        Wt[idx] = f2bf(v);
    }
}

// ---- CSR build: histogram by dst ----
__global__ __launch_bounds__(256) void hist_k(const int* __restrict__ edst,
                                              unsigned* __restrict__ hist) {
    int e = blockIdx.x * 256 + threadIdx.x;
    if (e < N_EDGES) atomicAdd(&hist[edst[e]], 1u);
}

// ---- scan pass 1: per-block sums ----
__global__ __launch_bounds__(1024) void scan_part(const unsigned* __restrict__ hist,
                                                  unsigned* __restrict__ bsum) {
    __shared__ unsigned s[1024];
    int idx = blockIdx.x * 1024 + threadIdx.x;
    s[threadIdx.x] = (idx < N_NODES) ? hist[idx] : 0u;
    __syncthreads();
    for (int off = 512; off > 0; off >>= 1) {
        if (threadIdx.x < off) s[threadIdx.x] += s[threadIdx.x + off];
        __syncthreads();
    }
    if (threadIdx.x == 0) bsum[blockIdx.x] = s[0];
}

// ---- scan pass 2: serial exclusive scan of 98 block sums ----
__global__ void scan_top(const unsigned* __restrict__ bsum, unsigned* __restrict__ boff,
                         unsigned* __restrict__ rowptr) {
    if (threadIdx.x == 0) {
        unsigned run = 0;
        for (int b = 0; b < SCAN_NBLK; ++b) { boff[b] = run; run += bsum[b]; }
        rowptr[N_NODES] = N_EDGES;
    }
}

// ---- scan pass 3: intra-block exclusive scan + offset ----
__global__ __launch_bounds__(1024) void scan_low(const unsigned* __restrict__ hist,
                                                 const unsigned* __restrict__ boff,
                                                 unsigned* __restrict__ rowptr) {
    __shared__ unsigned s[1024];
    int idx = blockIdx.x * 1024 + threadIdx.x;
    unsigned own = (idx < N_NODES) ? hist[idx] : 0u;
    s[threadIdx.x] = own;
    __syncthreads();
    for (int off = 1; off < 1024; off <<= 1) {
        unsigned t = 0;
        if ((int)threadIdx.x >= off) t = s[threadIdx.x - off];
        __syncthreads();
        if ((int)threadIdx.x >= off) s[threadIdx.x] += t;
        __syncthreads();
    }
    if (idx < N_NODES) rowptr[idx] = boff[blockIdx.x] + s[threadIdx.x] - own;
}

// ---- CSR fill: packed edge records {src, type, norm, dir} at sorted positions ----
__global__ __launch_bounds__(256) void fill_k(
    const int* __restrict__ edst, const int* __restrict__ esrc,
    const int* __restrict__ etyp, const float* __restrict__ norm,
    const unsigned* __restrict__ rowptr, unsigned* __restrict__ cursor,
    int4* __restrict__ recs) {
    int e = blockIdx.x * 256 + threadIdx.x;
    if (e < N_EDGES) {
        int d = edst[e];
        unsigned pos = rowptr[d] + atomicAdd(&cursor[d], 1u);
        recs[pos] = make_int4(esrc[e], etyp[e], __float_as_int(norm[e]), (e < HALF_E) ? 1 : 0);
    }
}

// ---- gather aggregation: one wave per dst node; swizzled bf16 x-rows ----
// 4 edges in flight per iteration (8 outstanding VMEM) to cover gather latency.
__global__ __launch_bounds__(256) void aggregate(
    const float* __restrict__ rel, const unsigned* __restrict__ rowptr,
    const int4* __restrict__ recs, unsigned short* __restrict__ A) {
    int v = blockIdx.x * 4 + (threadIdx.x >> 6);
    int lane = threadIdx.x & 63;
    bool act = lane < 50;                    // lane owns dims [lane*4, lane*4+4)
    int col = lane * 4;
    int kx = 400 + col;                      // logical x position
    int kxb = (kx & ~31) | (kx & 7);         // swizzle-invariant part
    int kxs = (kx >> 3) & 3;                 // logical slot
    float4 aI = make_float4(0.f, 0.f, 0.f, 0.f);
    float4 aO = make_float4(0.f, 0.f, 0.f, 0.f);

    const unsigned short* __restrict__ Ab = A;
    auto xload = [&](int src) -> ushort4 {
        int s = (src >> 1) & 3;
        return *reinterpret_cast<const ushort4*>(
            Ab + (size_t)src * KTOT + kxb + ((kxs ^ s) << 3));
    };
    auto accum = [&](const int4& r, const ushort4& xv, const float4& rl) {
        float nz = __int_as_float(r.z);
        float mx = bf2f(xv.x) * rl.x * nz;
        float my = bf2f(xv.y) * rl.y * nz;
        float mz = bf2f(xv.z) * rl.z * nz;
        float mw = bf2f(xv.w) * rl.w * nz;
        if (r.w) { aI.x += mx; aI.y += my; aI.z += mz; aI.w += mw; }
        else     { aO.x += mx; aO.y += my; aO.z += mz; aO.w += mw; }
    };

    int beg = rowptr[v], end = rowptr[v + 1];
    int j = beg;
    for (; j + 3 < end; j += 4) {
        int4 r0 = recs[j];
        int4 r1 = recs[j + 1];
        int4 r2 = recs[j + 2];
        int4 r3 = recs[j + 3];
        if (act) {
            ushort4 x0 = xload(r0.x);
            ushort4 x1 = xload(r1.x);
            ushort4 x2 = xload(r2.x);
            ushort4 x3 = xload(r3.x);
            float4 rl0 = *reinterpret_cast<const float4*>(rel + r0.y * 200 + col);
            float4 rl1 = *reinterpret_cast<const float4*>(rel + r1.y * 200 + col);
            float4 rl2 = *reinterpret_cast<const float4*>(rel + r2.y * 200 + col);
            float4 rl3 = *reinterpret_cast<const float4*>(rel + r3.y * 200 + col);
            accum(r0, x0, rl0);
            accum(r1, x1, rl1);
            accum(r2, x2, rl2);
            accum(r3, x3, rl3);
        }
    }
    if (j + 1 < end) {
        int4 r0 = recs[j];
        int4 r1 = recs[j + 1];
        if (act) {
            ushort4 x0 = xload(r0.x);
            ushort4 x1 = xload(r1.x);
            float4 rl0 = *reinterpret_cast<const float4*>(rel + r0.y * 200 + col);
            float4 rl1 = *reinterpret_cast<const float4*>(rel + r1.y * 200 + col);
            accum(r0, x0, rl0);
            accum(r1, x1, rl1);
        }
        j += 2;
    }
    if (j < end) {
        int4 r0 = recs[j];
        if (act) {
            ushort4 x0 = xload(r0.x);
            float4 rl0 = *reinterpret_cast<const float4*>(rel + r0.y * 200 + col);
            accum(r0, x0, rl0);
        }
    }
    if (act) {
        int sv = (v >> 1) & 3;
        unsigned short* ar = A + (size_t)v * KTOT;
        ushort4 wI = make_ushort4(f2bf(aI.x), f2bf(aI.y), f2bf(aI.z), f2bf(aI.w));
        ushort4 wO = make_ushort4(f2bf(aO.x), f2bf(aO.y), f2bf(aO.z), f2bf(aO.w));
        *reinterpret_cast<ushort4*>(ar + swzk(col, sv))       = wI;
        *reinterpret_cast<ushort4*>(ar + swzk(200 + col, sv)) = wO;
    }
}

// ---- GEMM: out[v][n] = A_bf[v][:] . Wt[n][:] / 3 ; per-block BN partials ----
// 2-phase double-buffered pipeline (guide T3 minimum form):
//   STAGE(buf^1, c+1) via global_load_lds   <- loads fly during MFMA phase
//   ds_read buf (XOR-swizzled, 2-way=free) + 26 MFMA
//   one __syncthreads per chunk (vmcnt(0)+barrier)
__global__ __launch_bounds__(256) void gemm_nodes(
    const unsigned short* __restrict__ A, const unsigned short* __restrict__ Wt,
    float* __restrict__ out, float* __restrict__ PS, float* __restrict__ PQ) {
    __shared__ __align__(16) char lds[2][LDS_BUF_BYTES];
    int tid = threadIdx.x;
    int wave = tid >> 6, lane = tid & 63;
    int quad = lane >> 4, l15 = lane & 15;
    int row0 = blockIdx.x * 128;
    int pslot16 = ((quad ^ ((l15 >> 1) & 3)) << 4);   // physical 16B slot for reads

    // staging sources: wave stages A rows [(wave*2+p)*16, +16), lane -> (row lane>>2, slot lane&3)
    int sv0 = row0 + (wave * 2 + 0) * 16 + (lane >> 2);
    int sv1 = row0 + (wave * 2 + 1) * 16 + (lane >> 2);
    if (sv0 >= N_NODES) sv0 = N_NODES - 1;   // clamp; excluded from out/stats below
    if (sv1 >= N_NODES) sv1 = N_NODES - 1;
    const char* Ab = (const char*)A;
    const char* srcA0 = Ab + (size_t)sv0 * 1280 + (lane & 3) * 16;
    const char* srcA1 = Ab + (size_t)sv1 * 1280 + (lane & 3) * 16;
    const char* Wb = (const char*)Wt + lane * 16;

    // LDS read offsets
    int rdA0 = ((wave * 2 + 0) * 16 + l15) * 64 + pslot16;
    int rdA1 = ((wave * 2 + 1) * 16 + l15) * 64 + pslot16;
    int rdB  = LDS_W_OFF + l15 * 64 + pslot16;

    f32x4 acc[2][13];
#pragma unroll
    for (int i = 0; i < 2; ++i)
#pragma unroll
        for (int j = 0; j < 13; ++j) {
            acc[i][j].x = 0.f; acc[i][j].y = 0.f; acc[i][j].z = 0.f; acc[i][j].w = 0.f;
        }

    // prologue: stage chunk 0 into buf 0
    {
        char* lb = lds[0];
        gload16(srcA0, lb + (wave * 2 + 0) * 1024);
        gload16(srcA1, lb + (wave * 2 + 1) * 1024);
#pragma unroll
        for (int i = wave; i < 13; i += 4)
            gload16(Wb + i * 1024, lb + LDS_W_OFF + i * 1024);
    }
    __syncthreads();

    int cur = 0;
    for (int c = 0; c < CHUNKS; ++c) {
        if (c + 1 < CHUNKS) {            // stage next chunk into other buffer
            char* lb = lds[cur ^ 1];
            gload16(srcA0 + (c + 1) * 64, lb + (wave * 2 + 0) * 1024);
            gload16(srcA1 + (c + 1) * 64, lb + (wave * 2 + 1) * 1024);
            const char* wsrc = Wb + (size_t)(c + 1) * 13312;
#pragma unroll
            for (int i = wave; i < 13; i += 4)
                gload16(wsrc + i * 1024, lb + LDS_W_OFF + i * 1024);
        }
        const char* lb = lds[cur];
        bf16x8 a0 = *reinterpret_cast<const bf16x8*>(lb + rdA0);
        bf16x8 a1 = *reinterpret_cast<const bf16x8*>(lb + rdA1);
#pragma unroll
        for (int nt = 0; nt < 13; ++nt) {
            bf16x8 b = *reinterpret_cast<const bf16x8*>(lb + rdB + nt * 1024);
            acc[0][nt] = __builtin_amdgcn_mfma_f32_16x16x32_bf16(a0, b, acc[0][nt], 0, 0, 0);
            acc[1][nt] = __builtin_amdgcn_mfma_f32_16x16x32_bf16(a1, b, acc[1][nt], 0, 0, 0);
        }
        __syncthreads();
        cur ^= 1;
    }

    // epilogue: store /3; per-wave column stats -> LDS -> per-block partials
    float* redS = reinterpret_cast<float*>(lds[0]);        // [4][200]
    float* redQ = reinterpret_cast<float*>(lds[0]) + 800;  // [4][200]
#pragma unroll
    for (int nt = 0; nt < 13; ++nt) {
        int n = nt * 16 + l15;
        float s = 0.f, q = 0.f;
#pragma unroll
        for (int i = 0; i < 2; ++i) {
            int mbase = row0 + (wave * 2 + i) * 16 + quad * 4;
#pragma unroll
            for (int r = 0; r < 4; ++r) {
                float val = acc[i][nt][r] * (1.f / 3.f);
                int m = mbase + r;
                if (m < N_NODES) {
                    if (n < 200) out[m * 200 + n] = val;
                    s += val; q += val * val;
                }
            }
        }
        s += __shfl_xor(s, 16); s += __shfl_xor(s, 32);
        q += __shfl_xor(q, 16); q += __shfl_xor(q, 32);
        if (lane < 16 && n < 200) {
            redS[wave * 200 + n] = s;
            redQ[wave * 200 + n] = q;
        }
    }
    __syncthreads();
    if (tid < 200) {
        float s = redS[tid] + redS[200 + tid] + redS[400 + tid] + redS[600 + tid];
        float q = redQ[tid] + redQ[200 + tid] + redQ[400 + tid] + redQ[600 + tid];
        PS[blockIdx.x * 200 + tid] = s;
        PQ[blockIdx.x * 200 + tid] = q;
    }
}

// ---- BN: reduce 782 partials per column, emit scale/shift. grid = 200 blocks ----
__global__ __launch_bounds__(256) void bn_reduce(
    const float* __restrict__ PS, const float* __restrict__ PQ,
    const float* __restrict__ gamma, const float* __restrict__ beta,
    float* __restrict__ scale, float* __restrict__ shift) {
    __shared__ float ls[256], lq[256];
    int c = blockIdx.x;
    float s = 0.f, q = 0.f;
    for (int b = threadIdx.x; b < GEMM_NBLK; b += 256) {
        s += PS[b * 200 + c];
        q += PQ[b * 200 + c];
    }
    ls[threadIdx.x] = s; lq[threadIdx.x] = q;
    __syncthreads();
    for (int off = 128; off > 0; off >>= 1) {
        if (threadIdx.x < off) {
            ls[threadIdx.x] += ls[threadIdx.x + off];
            lq[threadIdx.x] += lq[threadIdx.x + off];
        }
        __syncthreads();
    }
    if (threadIdx.x == 0) {
        float mean = ls[0] * (1.f / N_NODES);
        float var = lq[0] * (1.f / N_NODES) - mean * mean;
        float inv = rsqrtf(var + BN_EPS);
        float sc = inv * gamma[c];
        scale[c] = sc;
        shift[c] = beta[c] - mean * sc;
    }
}

__global__ __launch_bounds__(256) void bn_apply(
    float* __restrict__ h, const float* __restrict__ scale, const float* __restrict__ shift) {
    __shared__ float ssc[200], ssh[200];
    if (threadIdx.x < 200) { ssc[threadIdx.x] = scale[threadIdx.x]; ssh[threadIdx.x] = shift[threadIdx.x]; }
    __syncthreads();
    const int total4 = N_NODES * 200 / 4;  // 5,000,000 float4
    int stride = gridDim.x * blockDim.x;
    for (int i = blockIdx.x * blockDim.x + threadIdx.x; i < total4; i += stride) {
        int c = (i % 50) * 4;
        float4 v = reinterpret_cast<float4*>(h)[i];
        v.x = v.x * ssc[c + 0] + ssh[c + 0];
        v.y = v.y * ssc[c + 1] + ssh[c + 1];
        v.z = v.z * ssc[c + 2] + ssh[c + 2];
        v.w = v.w * ssc[c + 3] + ssh[c + 3];
        reinterpret_cast<float4*>(h)[i] = v;
    }
}

// ---- rel_out = rel_repr @ w_rel (200x200 @ 200x200), fp32 exact ----
__global__ __launch_bounds__(256) void rel_out_k(
    const float* __restrict__ rel, const float* __restrict__ w, float* __restrict__ out) {
    int i = blockIdx.x, j = threadIdx.x;
    if (j < 200) {
        float acc = 0.f;
        for (int k = 0; k < 200; ++k) acc += rel[i * 200 + k] * w[k * 200 + j];
        out[i * 200 + j] = acc;
    }
}

extern "C" void kernel_launch(void* const* d_in, const int* in_sizes, int n_in,
                              void* d_out, int out_size, void* d_ws, size_t ws_size,
                              hipStream_t stream) {
    const float* x         = (const float*)d_in[0];
    const float* rel_repr  = (const float*)d_in[1];
    const float* edge_norm = (const float*)d_in[2];
    const float* in_w      = (const float*)d_in[3];
    const float* out_w     = (const float*)d_in[4];
    const float* loop_w    = (const float*)d_in[5];
    const float* loop_rel  = (const float*)d_in[6];
    const float* w_rel     = (const float*)d_in[7];
    const float* bn_gamma  = (const float*)d_in[8];
    const float* bn_beta   = (const float*)d_in[9];
    const int* edge_src    = (const int*)d_in[10];
    const int* edge_dst    = (const int*)d_in[11];
    const int* edge_type   = (const int*)d_in[12];

    float* out = (float*)d_out;
    char* ws = (char*)d_ws;
    unsigned short* A  = (unsigned short*)(ws + A_OFF);
    unsigned short* Wt = (unsigned short*)(ws + WT_OFF);
    unsigned* hist     = (unsigned*)(ws + HIST_OFF);
    unsigned* cursor   = (unsigned*)(ws + CURSOR_OFF);
    float* scale       = (float*)(ws + SCALE_OFF);
    float* shift       = (float*)(ws + SHIFT_OFF);
    unsigned* rowptr   = (unsigned*)(ws + ROWPTR_OFF);
    unsigned* bsum     = (unsigned*)(ws + BSUM_OFF);
    unsigned* boff     = (unsigned*)(ws + BOFF_OFF);
    int4* recs         = (int4*)(ws + REC_OFF);
    float* PS          = (float*)(ws + PS_OFF);
    float* PQ          = (float*)(ws + PQ_OFF);

    hipMemsetAsync(ws + ZERO_BASE, 0, ZERO_BYTES, stream);  // hist+cursor
    prep_k<<<PREP_NBLK, 256, 0, stream>>>(x, in_w, out_w, loop_w, loop_rel, A, Wt);
    hist_k<<<1563, 256, 0, stream>>>(edge_dst, hist);
    scan_part<<<SCAN_NBLK, 1024, 0, stream>>>(hist, bsum);
    scan_top<<<1, 64, 0, stream>>>(bsum, boff, rowptr);
    scan_low<<<SCAN_NBLK, 1024, 0, stream>>>(hist, boff, rowptr);
    fill_k<<<1563, 256, 0, stream>>>(edge_dst, edge_src, edge_type, edge_norm,
                                     rowptr, cursor, recs);
    aggregate<<<25000, 256, 0, stream>>>(rel_repr, rowptr, recs, A);
    gemm_nodes<<<GEMM_NBLK, 256, 0, stream>>>(A, Wt, out, PS, PQ);
    bn_reduce<<<200, 256, 0, stream>>>(PS, PQ, bn_gamma, bn_beta, scale, shift);
    bn_apply<<<1024, 256, 0, stream>>>(out, scale, shift);
    rel_out_k<<<200, 256, 0, stream>>>(rel_repr, w_rel, out + 20000000);
}